// Round 9
// baseline (369.755 us; speedup 1.0000x reference)
//
#include <hip/hip_runtime.h>

#define BQ 4096
#define NS 5

typedef __attribute__((ext_vector_type(8))) short bf16x8;
typedef __attribute__((ext_vector_type(4))) float f32x4;
typedef unsigned short ushortT;

// ---------------- ws layout: constexpr-computed, sizes in NATIVE elements ----------------
// R5-R7 failed from hand-computed offsets. Rule: sizes in element counts,
// BF() converts shorts->f32 slots, row counts rounded to GEMM tile multiples.
constexpr size_t BF(size_t nshorts) { return (nshorts + 1) / 2; }
constexpr size_t RUP(size_t x, size_t m) { return (x + m - 1) / m * m; }
constexpr size_t NR_XS = RUP(2 * (BQ + NS), 64);                 // 8256: k_gcn reads 64-row tiles
constexpr size_t WS_EMBB = 0;                                    // 200001*128 bf16
constexpr size_t SZ_EMBB = BF((size_t)200001 * 128);             // 12,800,064
constexpr size_t WS_QNB  = 0;                                    // 4096*256 f32, ALIASES embb head
constexpr size_t SZ_QNB  = (size_t)BQ * 256;                     // 1,048,576 (< SZ_EMBB ok)
constexpr size_t WS_XS   = WS_EMBB + SZ_EMBB;
constexpr size_t SZ_XS   = BF(NR_XS * 256);                      // 1,056,768
constexpr size_t WS_ABF  = WS_XS + SZ_XS;                        // 4096*256 bf16 (xq)
constexpr size_t SZ_ABF  = BF((size_t)BQ * 256);
constexpr size_t WS_P1B  = WS_ABF + SZ_ABF;                      // 512*256 bf16
constexpr size_t SZ_P1B  = BF((size_t)512 * 256);
constexpr size_t WS_P2B  = WS_P1B + SZ_P1B;                      // 256*512 bf16
constexpr size_t SZ_P2B  = BF((size_t)256 * 512);
constexpr size_t WS_WIHB = WS_P2B + SZ_P2B;                      // 1024*256 bf16
constexpr size_t SZ_WIHB = BF((size_t)1024 * 256);
constexpr size_t WS_WHHB = WS_WIHB + SZ_WIHB;                    // 1024*256 bf16
constexpr size_t SZ_WHHB = BF((size_t)1024 * 256);
constexpr size_t WS_GWB  = WS_WHHB + SZ_WHHB;                    // 128*256 bf16
constexpr size_t SZ_GWB  = BF((size_t)128 * 256);
constexpr size_t WS_SNB  = WS_GWB + SZ_GWB;                      // 5*256 f32
constexpr size_t WS_H1G  = WS_SNB + NS * 256;                    // 5*512 f32
constexpr size_t WS_ZB   = WS_H1G + NS * 512;                    // 5*256 f32
constexpr size_t WS_SG   = WS_ZB + NS * 256;                     // 256 f32
constexpr size_t WS_SN   = WS_SG + 256;
constexpr size_t WS_SWL  = WS_SN + 256;                          // 1024 f32
constexpr size_t WS_BL   = WS_SWL + 1024;                        // 1024 f32
constexpr size_t WS_TOTAL = WS_BL + 1024;                        // 14,804,160 f32 = 59.2 MB
static_assert(WS_ABF - WS_XS == 1056768, "XS size (8256 rows x 256 bf16)");
static_assert(WS_P1B - WS_ABF == 524288, "ABF size (4096x256 bf16)");

__device__ __forceinline__ float wave_allreduce(float v) {
#pragma unroll
  for (int off = 32; off > 0; off >>= 1) v += __shfl_xor(v, off, 64);
  return v;
}
__device__ __forceinline__ float block_allreduce(float v, float* buf) {
  v = wave_allreduce(v);
  __syncthreads();
  if ((threadIdx.x & 63) == 0) buf[threadIdx.x >> 6] = v;
  __syncthreads();
  return buf[0] + buf[1] + buf[2] + buf[3];
}
__device__ __forceinline__ float sigm(float x) { return 1.0f / (1.0f + expf(-x)); }
__device__ __forceinline__ ushortT f2bf(float f) {
  unsigned int u = __float_as_uint(f);
  unsigned int r = (u + 0x7fffu + ((u >> 16) & 1u)) >> 16;
  return (ushortT)r;
}
__device__ __forceinline__ float bf2f(ushortT u) {
  return __uint_as_float(((unsigned int)u) << 16);
}
__device__ __forceinline__ float dot4(float4 a, float4 b) {
  return a.x * b.x + a.y * b.y + a.z * b.z + a.w * b.w;
}

// ---------------- emb fp32 -> bf16 ----------------
__global__ __launch_bounds__(256) void k_ebf(const float* __restrict__ emb,
                                             ushortT* __restrict__ embb) {
  const int stride = gridDim.x * blockDim.x;
  const float4* e4 = (const float4*)emb;
  ushort4* o4 = (ushort4*)embb;
  for (int i = blockIdx.x * blockDim.x + threadIdx.x; i < 6400032; i += stride) {
    float4 v = e4[i];
    ushort4 u;
    u.x = f2bf(v.x); u.y = f2bf(v.y); u.z = f2bf(v.z); u.w = f2bf(v.w);
    o4[i] = u;
  }
}

// ---------------- pack (bf16 weights) ----------------
__global__ void k_pack(const float* __restrict__ w_ih, const float* __restrict__ w_hh,
                       const float* __restrict__ p1w, const float* __restrict__ p2w,
                       const float* __restrict__ gcn_w,
                       const float* __restrict__ b_ih, const float* __restrict__ b_hh,
                       ushortT* __restrict__ p1b16, ushortT* __restrict__ p2b16,
                       ushortT* __restrict__ wihb, ushortT* __restrict__ whhb,
                       ushortT* __restrict__ gwb, float* __restrict__ bL) {
  const int stride = gridDim.x * blockDim.x;
  const int gid = blockIdx.x * blockDim.x + threadIdx.x;
  for (int i = gid; i < 131072; i += stride) p1b16[i] = f2bf(p1w[i]);
  for (int i = gid; i < 131072; i += stride) p2b16[i] = f2bf(p2w[i]);
  for (int i = gid; i < 262144; i += stride) {
    int n = i >> 8, k = i & 255;
    int j = (n >> 2) + 512 * (n & 3);
    wihb[i] = f2bf(w_ih[j * 256 + k]);
    whhb[i] = f2bf(w_hh[j * 512 + k]);
  }
  for (int i = gid; i < 32768; i += stride) gwb[i] = f2bf(gcn_w[i]);
  for (int i = gid; i < 1024; i += stride) {
    int j = (i >> 2) + 512 * (i & 3);
    bL[i] = b_ih[j] + b_hh[j];
  }
}

// ---------------- gather+sum over bf16 emb ----------------
__global__ __launch_bounds__(256) void k_gather(
    const int* __restrict__ qlc, const int* __restrict__ qrc,
    const int* __restrict__ slc, const int* __restrict__ src_,
    const ushortT* __restrict__ embb, ushortT* __restrict__ XS) {
  const int r = blockIdx.x;
  const int b = r >> 1, side = r & 1;
  const int t = threadIdx.x;
  const int* cg;
  if (b < BQ) cg = (side ? qrc : qlc) + (size_t)b * 128;
  else        cg = (side ? src_ : slc) + (size_t)(b - BQ) * 128;
  __shared__ int connS[128];
  __shared__ __align__(16) float part[8][132];
  if (t < 128) connS[t] = cg[t];
  __syncthreads();
  const int s = t >> 5, l = t & 31;
  float4 acc = make_float4(0.f, 0.f, 0.f, 0.f);
#pragma unroll
  for (int kb = 0; kb < 2; kb++) {
    int im[8];
#pragma unroll
    for (int k = 0; k < 8; k++) im[k] = connS[(kb * 8 + k) * 8 + s];
    ushort4 v[8];
#pragma unroll
    for (int k = 0; k < 8; k++)
      v[k] = ((const ushort4*)(embb + (size_t)im[k] * 128))[l];
#pragma unroll
    for (int k = 0; k < 8; k++) {
      acc.x += bf2f(v[k].x); acc.y += bf2f(v[k].y);
      acc.z += bf2f(v[k].z); acc.w += bf2f(v[k].w);
    }
  }
  *(float4*)&part[s][l * 4] = acc;
  __syncthreads();
  const int hf = t >> 7, dd = t & 127;
  float sum = part[hf][dd] + part[2 + hf][dd] + part[4 + hf][dd] + part[6 + hf][dd];
  XS[(size_t)r * 256 + t] = f2bf(sum);
}

// ---------------- GCN matvec as MFMA GEMM + tanh/deg epilogue ----------------
__global__ __launch_bounds__(256) void k_gcn(
    const ushortT* __restrict__ XS, const ushortT* __restrict__ gwb,
    const float* __restrict__ gcn_bias,
    const int* __restrict__ qld, const int* __restrict__ qrd,
    const int* __restrict__ sld, const int* __restrict__ srd,
    float* __restrict__ qnb, float* __restrict__ snb, ushortT* __restrict__ xq) {
  __shared__ short As[64 * 40];
  __shared__ short Bs[128 * 40];
  __shared__ int degl[32], degr[32];
  const int t = threadIdx.x;
  const int row0 = blockIdx.x * 64;
  if (t < 32) {
    int b = (row0 >> 1) + t;
    int dl = 1, dr = 1;
    if (b < BQ) { dl = qld[b]; dr = qrd[b]; }
    else if (b < BQ + NS) { dl = sld[b - BQ]; dr = srd[b - BQ]; }
    degl[t] = (dl > 0) ? dl : 1;
    degr[t] = (dr > 0) ? dr : 1;
  }
  const int wave = t >> 6, lane = t & 63;
  const int wm = wave >> 1, wn = wave & 1, quad = lane >> 4, mr = lane & 15;
  f32x4 acc[2][4];
#pragma unroll
  for (int mi = 0; mi < 2; mi++)
#pragma unroll
    for (int ni = 0; ni < 4; ni++) acc[mi][ni] = (f32x4){0.f, 0.f, 0.f, 0.f};
  const int arow = t >> 2, akc = t & 3;
  for (int k0 = 0; k0 < 256; k0 += 32) {
    float4 av = *(const float4*)(XS + (size_t)(row0 + arow) * 256 + k0 + akc * 8);
    float4 bv0 = *(const float4*)(gwb + (size_t)arow * 256 + k0 + akc * 8);
    float4 bv1 = *(const float4*)(gwb + (size_t)(64 + arow) * 256 + k0 + akc * 8);
    __syncthreads();
    *(float4*)&As[arow * 40 + akc * 8] = av;
    *(float4*)&Bs[arow * 40 + akc * 8] = bv0;
    *(float4*)&Bs[(64 + arow) * 40 + akc * 8] = bv1;
    __syncthreads();
    bf16x8 af[2], bfr[4];
#pragma unroll
    for (int mi = 0; mi < 2; mi++)
      af[mi] = *(const bf16x8*)&As[(wm * 32 + mi * 16 + mr) * 40 + quad * 8];
#pragma unroll
    for (int ni = 0; ni < 4; ni++)
      bfr[ni] = *(const bf16x8*)&Bs[(wn * 64 + ni * 16 + mr) * 40 + quad * 8];
#pragma unroll
    for (int mi = 0; mi < 2; mi++)
#pragma unroll
      for (int ni = 0; ni < 4; ni++)
        acc[mi][ni] = __builtin_amdgcn_mfma_f32_16x16x32_bf16(af[mi], bfr[ni], acc[mi][ni], 0, 0, 0);
  }
#pragma unroll
  for (int mi = 0; mi < 2; mi++) {
#pragma unroll
    for (int ni = 0; ni < 4; ni++) {
      const int col = wn * 64 + ni * 16 + mr;
      const int rb = row0 + wm * 32 + mi * 16 + quad * 4;
      const float bs = 64.0f * gcn_bias[col];
#pragma unroll
      for (int reg = 0; reg < 4; reg++) {
        const int row = rb + reg;
        const int b = row >> 1, side = row & 1;
        if (b >= BQ + NS) continue;
        const int li = (row >> 1) - (row0 >> 1);
        const int deg = side ? degr[li] : degl[li];
        float val = tanhf((acc[mi][ni][reg] + bs) / (float)deg);
        if (b < BQ) {
          const size_t o = (size_t)b * 256 + side * 128 + col;
          qnb[o] = val;
          xq[o] = f2bf(val);
        } else {
          snb[(size_t)(b - BQ) * 256 + side * 128 + col] = val;
        }
      }
    }
  }
}

// ---------------- support path ----------------
__global__ __launch_bounds__(256) void k_sup1(
    const float* __restrict__ snb, const float* __restrict__ p1w,
    const float* __restrict__ p1b, float* __restrict__ h1g) {
  const int w = blockIdx.x * 4 + (threadIdx.x >> 6);
  const int lane = threadIdx.x & 63;
  const int r = w >> 9, j = w & 511;
  float4 x = *(const float4*)&snb[r * 256 + lane * 4];
  float4 wv = *(const float4*)&p1w[(size_t)j * 256 + lane * 4];
  float s = wave_allreduce(dot4(x, wv));
  if (lane == 0) h1g[r * 512 + j] = fmaxf(s + p1b[j], 0.f);
}

__global__ __launch_bounds__(256) void k_sup2(
    const float* __restrict__ snb, const float* __restrict__ h1g,
    const float* __restrict__ p2w, const float* __restrict__ p2b,
    float* __restrict__ zb) {
  const int w = blockIdx.x * 4 + (threadIdx.x >> 6);
  const int lane = threadIdx.x & 63;
  const int r = w >> 8, tt = w & 255;
  float4 h0 = *(const float4*)&h1g[r * 512 + lane * 4];
  float4 h1 = *(const float4*)&h1g[r * 512 + 256 + lane * 4];
  float4 w0 = *(const float4*)&p2w[(size_t)tt * 512 + lane * 4];
  float4 w1 = *(const float4*)&p2w[(size_t)tt * 512 + 256 + lane * 4];
  float s = wave_allreduce(dot4(h0, w0) + dot4(h1, w1));
  if (lane == 0) zb[r * 256 + tt] = s + p2b[tt] + snb[r * 256 + tt];
}

__global__ __launch_bounds__(256) void k_sup3(
    const float* __restrict__ zb, const float* __restrict__ ln_g,
    const float* __restrict__ ln_b, float* __restrict__ sg, float* __restrict__ sn) {
  const int t = threadIdx.x;
  __shared__ float rbuf[4];
  float acc = 0.f;
  for (int r = 0; r < NS; r++) {
    float z = zb[r * 256 + t];
    float s = block_allreduce(z, rbuf);
    float mu = s * (1.f / 256.f);
    float dz = z - mu;
    float s2 = block_allreduce(dz * dz, rbuf);
    float rstd = 1.f / (sqrtf(s2 * (1.f / 255.f)) + 1e-6f);
    acc += ln_g[t] * dz * rstd + ln_b[t];
    __syncthreads();
  }
  float g = acc * (1.f / (float)NS);
  sg[t] = g;
  float n2 = block_allreduce(g * g, rbuf);
  sn[t] = g / fmaxf(sqrtf(n2), 1e-12f);
}

__global__ __launch_bounds__(256) void k_sup4(
    const float* __restrict__ sg, const float* __restrict__ w_hh,
    float* __restrict__ sWl) {
  const int n = blockIdx.x * 4 + (threadIdx.x >> 6);
  const int lane = threadIdx.x & 63;
  const int j = (n >> 2) + 512 * (n & 3);
  float4 x = *(const float4*)&sg[lane * 4];
  float4 wv = *(const float4*)&w_hh[(size_t)j * 512 + 256 + lane * 4];
  float s = wave_allreduce(dot4(x, wv));
  if (lane == 0) sWl[n] = s;
}

// ---------------- fused SE + LSTM + output, 16 rows per block ----------------
template <int KCH>
__device__ __forceinline__ void gemm_pass(
    const ushortT* __restrict__ Alds, int astride,
    const ushortT* __restrict__ Bg, int bstride, int colbase,
    float (*Cs)[260], int wave, int lane) {
  const int quad = lane >> 4, mr = lane & 15;
  f32x4 acc[4];
#pragma unroll
  for (int ni = 0; ni < 4; ni++) acc[ni] = (f32x4){0.f, 0.f, 0.f, 0.f};
  const ushortT* arow = Alds + mr * astride + quad * 8;
#pragma unroll
  for (int k0 = 0; k0 < KCH; k0++) {
    bf16x8 af = *(const bf16x8*)(arow + k0 * 32);
#pragma unroll
    for (int ni = 0; ni < 4; ni++) {
      const ushortT* bp = Bg + (size_t)(colbase + wave * 64 + ni * 16 + mr) * bstride
                          + k0 * 32 + quad * 8;
      bf16x8 bf = *(const bf16x8*)bp;
      acc[ni] = __builtin_amdgcn_mfma_f32_16x16x32_bf16(af, bf, acc[ni], 0, 0, 0);
    }
  }
#pragma unroll
  for (int ni = 0; ni < 4; ni++)
#pragma unroll
    for (int reg = 0; reg < 4; reg++)
      Cs[quad * 4 + reg][wave * 64 + ni * 16 + mr] = acc[ni][reg];
}

__global__ __launch_bounds__(256) void k_fused(
    const ushortT* __restrict__ xq, const float* __restrict__ qnb,
    const ushortT* __restrict__ p1b16, const float* __restrict__ p1bias,
    const ushortT* __restrict__ p2b16, const float* __restrict__ p2bias,
    const float* __restrict__ ln_g, const float* __restrict__ ln_b,
    const ushortT* __restrict__ wihb, const ushortT* __restrict__ whhb,
    const float* __restrict__ bL, const float* __restrict__ sWl,
    const float* __restrict__ sn, float* __restrict__ outv) {
  __shared__ __align__(16) ushortT xwS[16 * 1024];   // 32 KB; h1S overlays (16*520)
  __shared__ __align__(16) ushortT hS[16 * 272];     // 8.5 KB: xq -> qg -> h
  __shared__ __align__(16) float Cs[16][260];        // 16.6 KB
  __shared__ float snS[256];
  const int t = threadIdx.x;
  const int wave = t >> 6, lane = t & 63;
  const int row0 = blockIdx.x * 16;
  ushortT* h1S = xwS;  // stride 520

  {
    const int r = t >> 4, c = (t & 15) * 16;
    const float4* src = (const float4*)(xq + (size_t)(row0 + r) * 256 + c);
    *(float4*)&hS[r * 272 + c] = src[0];
    *(float4*)&hS[r * 272 + c + 8] = src[1];
    snS[t] = sn[t];
  }
  __syncthreads();

  // ---- proj1: h1 = relu(xq @ p1^T + b1), N=512 (2 passes) ----
#pragma unroll
  for (int p = 0; p < 2; p++) {
    gemm_pass<8>(hS, 272, p1b16, 256, p * 256, Cs, wave, lane);
    __syncthreads();
    const int c4 = (t & 63) * 4;
#pragma unroll
    for (int i = 0; i < 4; i++) {
      const int row = (t >> 6) + 4 * i;
      float4 v = *(const float4*)&Cs[row][c4];
      float4 bb = *(const float4*)&p1bias[p * 256 + c4];
      ushort4 o;
      o.x = f2bf(fmaxf(v.x + bb.x, 0.f));
      o.y = f2bf(fmaxf(v.y + bb.y, 0.f));
      o.z = f2bf(fmaxf(v.z + bb.z, 0.f));
      o.w = f2bf(fmaxf(v.w + bb.w, 0.f));
      *(ushort4*)&h1S[row * 520 + p * 256 + c4] = o;
    }
    __syncthreads();
  }

  // ---- proj2 + residual + two-pass LN -> q (Cs fp32, hS bf16) ----
  gemm_pass<16>(h1S, 520, p2b16, 512, 0, Cs, wave, lane);
  __syncthreads();
  {
    const int row = t >> 4, li = t & 15;
    float4 zr[4];
    float sum = 0.f;
#pragma unroll
    for (int j = 0; j < 4; j++) {
      const int c = li * 16 + j * 4;
      float4 v = *(const float4*)&Cs[row][c];
      float4 bb = *(const float4*)&p2bias[c];
      float4 xv = *(const float4*)&qnb[(size_t)(row0 + row) * 256 + c];
      v.x += bb.x + xv.x; v.y += bb.y + xv.y;
      v.z += bb.z + xv.z; v.w += bb.w + xv.w;
      zr[j] = v;
      sum += v.x + v.y + v.z + v.w;
    }
#pragma unroll
    for (int m = 1; m < 16; m <<= 1) sum += __shfl_xor(sum, m, 64);
    const float mu = sum * (1.f / 256.f);
    float s2 = 0.f;
#pragma unroll
    for (int j = 0; j < 4; j++) {
      float dx = zr[j].x - mu, dy = zr[j].y - mu, dz = zr[j].z - mu, dw = zr[j].w - mu;
      s2 += dx * dx + dy * dy + dz * dz + dw * dw;
    }
#pragma unroll
    for (int m = 1; m < 16; m <<= 1) s2 += __shfl_xor(s2, m, 64);
    const float rstd = 1.f / (sqrtf(s2 * (1.f / 255.f)) + 1e-6f);
#pragma unroll
    for (int j = 0; j < 4; j++) {
      const int c = li * 16 + j * 4;
      float4 g = *(const float4*)&ln_g[c];
      float4 b = *(const float4*)&ln_b[c];
      float4 q;
      q.x = g.x * (zr[j].x - mu) * rstd + b.x;
      q.y = g.y * (zr[j].y - mu) * rstd + b.y;
      q.z = g.z * (zr[j].z - mu) * rstd + b.z;
      q.w = g.w * (zr[j].w - mu) * rstd + b.w;
      *(float4*)&Cs[row][c] = q;
      ushort4 o;
      o.x = f2bf(q.x); o.y = f2bf(q.y); o.z = f2bf(q.z); o.w = f2bf(q.w);
      *(ushort4*)&hS[row * 272 + c] = o;
    }
  }
  __syncthreads();

  const int l6 = t & 63;
  float q_reg[4][4], c_reg[4][4], h_reg[4][4];
#pragma unroll
  for (int i = 0; i < 4; i++)
#pragma unroll
    for (int p = 0; p < 4; p++)
      q_reg[i][p] = Cs[(t >> 6) + 4 * i][p * 64 + l6];
  __syncthreads();

  // ---- step 0: xW GEMM + first LSTM step + xw'=acc+bL+sW ----
#pragma unroll
  for (int p = 0; p < 4; p++) {
    gemm_pass<8>(hS, 272, wihb, 256, p * 256, Cs, wave, lane);
    __syncthreads();
    float4 sv = *(const float4*)&sWl[p * 256 + l6 * 4];
    float4 bb = *(const float4*)&bL[p * 256 + l6 * 4];
#pragma unroll
    for (int i = 0; i < 4; i++) {
      const int row = (t >> 6) + 4 * i;
      float4 gv = *(const float4*)&Cs[row][l6 * 4];
      gv.x += bb.x; gv.y += bb.y; gv.z += bb.z; gv.w += bb.w;
      float c0 = sigm(gv.x) * tanhf(gv.z);
      float h = q_reg[i][p] + sigm(gv.w) * tanhf(c0);
      c_reg[i][p] = c0;
      h_reg[i][p] = h;
      ushort4 xo;
      xo.x = f2bf(gv.x + sv.x); xo.y = f2bf(gv.y + sv.y);
      xo.z = f2bf(gv.z + sv.z); xo.w = f2bf(gv.w + sv.w);
      *(ushort4*)&xwS[row * 1024 + p * 256 + l6 * 4] = xo;
      if (p == 3) {
#pragma unroll
        for (int pp = 0; pp < 4; pp++)
          hS[row * 272 + pp * 64 + l6] = f2bf(h_reg[i][pp]);
      }
    }
    __syncthreads();
  }

  // ---- steps 1..3: hh GEMM + gate math ----
  float dotv[4] = {0.f, 0.f, 0.f, 0.f}, nrmv[4] = {0.f, 0.f, 0.f, 0.f};
  for (int s = 1; s < 4; s++) {
    const int last = (s == 3);
#pragma unroll
    for (int p = 0; p < 4; p++) {
      gemm_pass<8>(hS, 272, whhb, 256, p * 256, Cs, wave, lane);
      __syncthreads();
#pragma unroll
      for (int i = 0; i < 4; i++) {
        const int row = (t >> 6) + 4 * i;
        float4 gv = *(const float4*)&Cs[row][l6 * 4];
        ushort4 xv = *(const ushort4*)&xwS[row * 1024 + p * 256 + l6 * 4];
        gv.x += bf2f(xv.x); gv.y += bf2f(xv.y);
        gv.z += bf2f(xv.z); gv.w += bf2f(xv.w);
        float c = sigm(gv.y) * c_reg[i][p] + sigm(gv.x) * tanhf(gv.z);
        float h = q_reg[i][p] + sigm(gv.w) * tanhf(c);
        c_reg[i][p] = c;
        if (last) {
          dotv[i] += h * snS[p * 64 + l6];
          nrmv[i] += h * h;
        } else {
          h_reg[i][p] = h;
          if (p == 3) {
#pragma unroll
            for (int pp = 0; pp < 4; pp++)
              hS[row * 272 + pp * 64 + l6] = f2bf(h_reg[i][pp]);
          }
        }
      }
      __syncthreads();
    }
  }

#pragma unroll
  for (int i = 0; i < 4; i++) {
    float d = wave_allreduce(dotv[i]);
    float n = wave_allreduce(nrmv[i]);
    if (lane == 0) outv[row0 + wave + 4 * i] = d / fmaxf(sqrtf(n), 1e-12f);
  }
}

extern "C" void kernel_launch(void* const* d_in, const int* in_sizes, int n_in,
                              void* d_out, int out_size, void* d_ws, size_t ws_size,
                              hipStream_t stream) {
  const int* q_l_conn = (const int*)d_in[2];
  const int* q_l_deg  = (const int*)d_in[3];
  const int* q_r_conn = (const int*)d_in[4];
  const int* q_r_deg  = (const int*)d_in[5];
  const int* s_l_conn = (const int*)d_in[6];
  const int* s_l_deg  = (const int*)d_in[7];
  const int* s_r_conn = (const int*)d_in[8];
  const int* s_r_deg  = (const int*)d_in[9];
  const float* emb      = (const float*)d_in[10];
  const float* gcn_w    = (const float*)d_in[11];
  const float* gcn_bias = (const float*)d_in[12];
  const float* proj1_w  = (const float*)d_in[13];
  const float* proj1_b  = (const float*)d_in[14];
  const float* proj2_w  = (const float*)d_in[15];
  const float* proj2_b  = (const float*)d_in[16];
  const float* ln_g     = (const float*)d_in[17];
  const float* ln_b     = (const float*)d_in[18];
  const float* w_ih     = (const float*)d_in[19];
  const float* w_hh     = (const float*)d_in[20];
  const float* b_ih     = (const float*)d_in[21];
  const float* b_hh     = (const float*)d_in[22];

  float* ws = (float*)d_ws;
  ushortT* embb  = (ushortT*)(ws + WS_EMBB);
  float* qnb     = ws + WS_QNB;  // aliases embb head (embb dead after k_gather)
  ushortT* XS    = (ushortT*)(ws + WS_XS);
  ushortT* abf   = (ushortT*)(ws + WS_ABF);
  ushortT* p1b16 = (ushortT*)(ws + WS_P1B);
  ushortT* p2b16 = (ushortT*)(ws + WS_P2B);
  ushortT* wihb  = (ushortT*)(ws + WS_WIHB);
  ushortT* whhb  = (ushortT*)(ws + WS_WHHB);
  ushortT* gwb   = (ushortT*)(ws + WS_GWB);
  float* snb   = ws + WS_SNB;
  float* h1g   = ws + WS_H1G;
  float* zb    = ws + WS_ZB;
  float* sg    = ws + WS_SG;
  float* sn    = ws + WS_SN;
  float* sWl   = ws + WS_SWL;
  float* bL    = ws + WS_BL;
  float* out   = (float*)d_out;

  hipLaunchKernelGGL(k_ebf, dim3(2048), dim3(256), 0, stream, emb, embb);
  hipLaunchKernelGGL(k_pack, dim3(512), dim3(256), 0, stream,
                     w_ih, w_hh, proj1_w, proj2_w, gcn_w, b_ih, b_hh,
                     p1b16, p2b16, wihb, whhb, gwb, bL);
  hipLaunchKernelGGL(k_gather, dim3(2 * (BQ + NS)), dim3(256), 0, stream,
                     q_l_conn, q_r_conn, s_l_conn, s_r_conn, embb, XS);
  hipLaunchKernelGGL(k_gcn, dim3(129), dim3(256), 0, stream,
                     XS, gwb, gcn_bias, q_l_deg, q_r_deg, s_l_deg, s_r_deg,
                     qnb, snb, abf);
  hipLaunchKernelGGL(k_sup1, dim3(640), dim3(256), 0, stream, snb, proj1_w, proj1_b, h1g);
  hipLaunchKernelGGL(k_sup2, dim3(320), dim3(256), 0, stream, snb, h1g, proj2_w, proj2_b, zb);
  hipLaunchKernelGGL(k_sup3, dim3(1), dim3(256), 0, stream, zb, ln_g, ln_b, sg, sn);
  hipLaunchKernelGGL(k_sup4, dim3(256), dim3(256), 0, stream, sg, w_hh, sWl);
  hipLaunchKernelGGL(k_fused, dim3(BQ / 16), dim3(256), 0, stream,
                     abf, qnb, p1b16, proj1_b, p2b16, proj2_b, ln_g, ln_b,
                     wihb, whhb, bL, sWl, sn, out);
}